// Round 7
// baseline (386.686 us; speedup 1.0000x reference)
//
#include <hip/hip_runtime.h>
#include <math.h>

#define NROWS   16384
#define NBOOKS  128
#define NWORDS  64
#define LWORD   32
#define DIMS    4096
#define T2K     28.8539008177792681472f   /* 20 * log2(e) */
#define Z_ELEMS 67108864ull               /* 16384*4096   */

typedef __attribute__((ext_vector_type(8))) short s16x8;
typedef __attribute__((ext_vector_type(4))) float f32x4;
typedef __attribute__((ext_vector_type(4))) unsigned int u32x4;

/* ws layout (bytes) */
#define CBT_OFF  0u           /* f32 [128][64][32] np-normalized codewords      */
#define C2T_OFF  1048576u     /* f32 [128][64]                                  */
#define FR_OFF   1114112u     /* merged frags: [(b*4+wb)*64+lane][4 x 16B]      */
                              /*   slot0=ch, slot1=cl, slot2=a2, slot3=ci(f32x4)*/
#define CTR_OFF  3211264u     /* u32 rescan counter                             */
#define LIST_OFF 3211392u     /* u32[131072] packed (row<<7)|b                  */
#define LIST_CAP 131072u

__device__ __forceinline__ unsigned short f2bf(float f) {
    unsigned int u = __float_as_uint(f);
    unsigned int r = (u + 0x7FFFu + ((u >> 16) & 1u)) >> 16;   /* RNE */
    return (unsigned short)r;
}
__device__ __forceinline__ float bf2f(unsigned short s) {
    return __uint_as_float(((unsigned int)s) << 16);
}
__device__ __forceinline__ unsigned int cvtpk_bf16(float lo, float hi) {
    unsigned int r;
    asm("v_cvt_pk_bf16_f32 %0, %1, %2" : "=v"(r) : "v"(lo), "v"(hi));  /* RNE */
    return r;
}

/* numpy pairwise-sum replica for n=32 f32 (exact order, no contraction) */
__device__ __forceinline__ float np_sum32(const float* a) {
#pragma clang fp contract(off)
    float r0 = a[0], r1 = a[1], r2 = a[2], r3 = a[3];
    float r4 = a[4], r5 = a[5], r6 = a[6], r7 = a[7];
    r0 += a[8];  r1 += a[9];  r2 += a[10]; r3 += a[11];
    r4 += a[12]; r5 += a[13]; r6 += a[14]; r7 += a[15];
    r0 += a[16]; r1 += a[17]; r2 += a[18]; r3 += a[19];
    r4 += a[20]; r5 += a[21]; r6 += a[22]; r7 += a[23];
    r0 += a[24]; r1 += a[25]; r2 += a[26]; r3 += a[27];
    r4 += a[28]; r5 += a[29]; r6 += a[30]; r7 += a[31];
    return ((r0 + r1) + (r2 + r3)) + ((r4 + r5) + (r6 + r7));
}

/* ---------- kernel 1: fused np-exact normalize + frag build (128 blk x 64 thr) ---------- */
__global__ __launch_bounds__(64) void prepC_kernel(const float* __restrict__ C,
                                                   float* __restrict__ cbT,
                                                   float* __restrict__ c2T,
                                                   s16x8* __restrict__ fr,
                                                   unsigned int* __restrict__ ctr) {
    __shared__ float cb_s[NWORDS][33];
    __shared__ float c2_s[NWORDS];
    int b = blockIdx.x;
    int w = threadIdx.x;
    if (b == 0 && w == 0) ctr[0] = 0u;

    float cb[LWORD];
    float c2;
    {   /* np-exact normalize — verbatim verified math */
#pragma clang fp contract(off)
        const float* src = C + (size_t)w * DIMS + b * LWORD;
        float v[LWORD];
        #pragma unroll
        for (int q = 0; q < 8; ++q)
            *(float4*)&v[4 * q] = *(const float4*)&src[4 * q];
        float sq[LWORD];
        #pragma unroll
        for (int l = 0; l < LWORD; ++l) sq[l] = v[l] * v[l];
        float nrm = fmaxf(sqrtf(np_sum32(sq)), 1e-12f);
        #pragma unroll
        for (int l = 0; l < LWORD; ++l) cb[l] = v[l] / nrm;
        float sq2[LWORD];
        #pragma unroll
        for (int l = 0; l < LWORD; ++l) sq2[l] = cb[l] * cb[l];
        c2 = np_sum32(sq2);
    }
    float* dst = cbT + ((size_t)b * NWORDS + w) * LWORD;
    #pragma unroll
    for (int q = 0; q < 8; ++q)
        *(float4*)&dst[4 * q] = *(const float4*)&cb[4 * q];
    c2T[b * NWORDS + w] = c2;
    #pragma unroll
    for (int l = 0; l < LWORD; ++l) cb_s[w][l] = cb[l];
    c2_s[w] = c2;
    __syncthreads();

    int lr = w & 15, lh = w >> 4;
    #pragma unroll
    for (int wb = 0; wb < 4; ++wb) {
        s16x8 ch8, cl8, a28;
        #pragma unroll
        for (int i = 0; i < 8; ++i) {
            float f = cb_s[wb * 16 + lr][lh * 8 + i];
            unsigned short hh = f2bf(f);
            ch8[i] = (short)hh;
            cl8[i] = (short)f2bf(f - bf2f(hh));
            /* a2 slot wb: mb = wb>>1, kc = wb&1 (same mapping as verified fragC) */
            a28[i] = (short)f2bf(cb_s[(wb & 1) * 32 + lh * 8 + i][(wb >> 1) * 16 + lr]);
        }
        f32x4 civ = {-0.5f * c2_s[wb * 16 + lh * 4 + 0],
                     -0.5f * c2_s[wb * 16 + lh * 4 + 1],
                     -0.5f * c2_s[wb * 16 + lh * 4 + 2],
                     -0.5f * c2_s[wb * 16 + lh * 4 + 3]};
        s16x8* d = fr + ((size_t)(b * 4 + wb) * 64 + w) * 4;
        d[0] = ch8;
        d[1] = cl8;
        d[2] = a28;
        d[3] = __builtin_bit_cast(s16x8, civ);
    }
}

/* ---------- kernel 2: hot path — 16 rows/block, 32-book pipelined loop ---------- */
__global__ __launch_bounds__(256, 3) void softpq_mfma(const float* __restrict__ x,
                                                      const s16x8* __restrict__ fr,
                                                      unsigned int* __restrict__ ctr,
                                                      unsigned int* __restrict__ list,
                                                      float* __restrict__ out) {
    __shared__ __align__(16) unsigned short ps_s[4][16][72];   /* 9216 B */
    __shared__ float idx_s[4][32][17];                         /* 8704 B */

    int u = blockIdx.x;                      /* XCD-chunked row-tile remap */
    int L = (u & 7) * 128 + (u >> 3);
    int r0 = L * 16;
    int t = threadIdx.x;
    int lane = t & 63, wid = t >> 6;
    int h = lane >> 4, c = lane & 15;

    const float* xrowp = x + (size_t)(r0 + c) * DIMS + h * 8;
    float* zrowp = out + (size_t)(r0 + c) * DIMS + h * 4;
    const s16x8* frl = fr + (size_t)lane * 4;

    /* prefetch x for k=0 */
    float4 nxa = *(const float4*)(xrowp + (wid * 32) * LWORD);
    float4 nxb = *(const float4*)(xrowp + (wid * 32) * LWORD + 4);

    for (int k = 0; k < 32; ++k) {
        int b = wid * 32 + k;
        float4 cxa = nxa, cxb = nxb;
        if (k < 31) {                         /* issue next book's x early */
            nxa = *(const float4*)(xrowp + (size_t)(b + 1) * LWORD);
            nxb = *(const float4*)(xrowp + (size_t)(b + 1) * LWORD + 4);
        }
        /* frag loads: 4 x 64B contiguous per lane (L2-hot) */
        const s16x8* fp = frl + (size_t)b * 1024;
        s16x8 chf[4], clf[4], a2f[4];
        f32x4 ci[4];
        #pragma unroll
        for (int wb = 0; wb < 4; ++wb) {
            const s16x8* q = fp + (size_t)wb * 256;
            chf[wb] = q[0];
            clf[wb] = q[1];
            a2f[wb] = q[2];
            ci[wb]  = __builtin_bit_cast(f32x4, q[3]);
        }

        /* split x into bf16 hi + residual (verbatim) */
        float xf[8] = {cxa.x, cxa.y, cxa.z, cxa.w, cxb.x, cxb.y, cxb.z, cxb.w};
        unsigned int xhu[4], xlu[4];
        #pragma unroll
        for (int j = 0; j < 4; ++j) {
            float f0 = xf[2 * j], f1 = xf[2 * j + 1];
            unsigned int ph = cvtpk_bf16(f0, f1);
            float h0 = __uint_as_float(ph << 16);
            float h1 = __uint_as_float(ph & 0xffff0000u);
            xhu[j] = ph;
            xlu[j] = cvtpk_bf16(f0 - h0, f1 - h1);
        }
        u32x4 thv = {xhu[0], xhu[1], xhu[2], xhu[3]};
        u32x4 tlv = {xlu[0], xlu[1], xlu[2], xlu[3]};
        s16x8 xhv = __builtin_bit_cast(s16x8, thv);
        s16x8 xlv = __builtin_bit_cast(s16x8, tlv);

        /* 12 S-MFMAs; acc = dot - c2/2 (x2 shift-invariant) */
        __builtin_amdgcn_s_setprio(1);
        f32x4 acc[4];
        #pragma unroll
        for (int wb = 0; wb < 4; ++wb) {
            f32x4 a = ci[wb];
            a = __builtin_amdgcn_mfma_f32_16x16x32_bf16(chf[wb], xhv, a, 0, 0, 0);
            a = __builtin_amdgcn_mfma_f32_16x16x32_bf16(chf[wb], xlv, a, 0, 0, 0);
            a = __builtin_amdgcn_mfma_f32_16x16x32_bf16(clf[wb], xhv, a, 0, 0, 0);
            acc[wb] = a;
        }
        __builtin_amdgcn_s_setprio(0);

        /* ---- tail: verbatim verified numerics ---- */
        float q0 = fmaxf(fmaxf(acc[0][0], acc[0][1]), acc[0][2]);
        float q1 = fmaxf(fmaxf(acc[0][3], acc[1][0]), acc[1][1]);
        float q2 = fmaxf(fmaxf(acc[1][2], acc[1][3]), acc[2][0]);
        float q3 = fmaxf(fmaxf(acc[2][1], acc[2][2]), acc[2][3]);
        float q4 = fmaxf(fmaxf(acc[3][0], acc[3][1]), acc[3][2]);
        float m1 = fmaxf(fmaxf(fmaxf(q0, q1), q2), fmaxf(fmaxf(q3, q4), acc[3][3]));
        m1 = fmaxf(m1, __shfl_xor(m1, 16));
        m1 = fmaxf(m1, __shfl_xor(m1, 32));

        float thr = m1 - 2e-4f;
        int cnt = 0;
        #pragma unroll
        for (int wb = 0; wb < 4; ++wb)
            #pragma unroll
            for (int r = 0; r < 4; ++r) cnt += (acc[wb][r] > thr) ? 1 : 0;
        cnt += __shfl_xor(cnt, 16);
        cnt += __shfl_xor(cnt, 32);

        int wsel = 9999;
        #pragma unroll
        for (int wb = 0; wb < 4; ++wb)
            #pragma unroll
            for (int r = 0; r < 4; ++r)
                if (acc[wb][r] == m1) wsel = min(wsel, wb * 16 + h * 4 + r);
        wsel = min(wsel, __shfl_xor(wsel, 16));
        wsel = min(wsel, __shfl_xor(wsel, 32));

        float mqt = m1 * (-T2K);
        float p[16];
        float sum = 0.f;
        #pragma unroll
        for (int wb = 0; wb < 4; ++wb)
            #pragma unroll
            for (int r = 0; r < 4; ++r) {
                p[wb * 4 + r] = __builtin_amdgcn_exp2f(fmaf(T2K, acc[wb][r], mqt));
                sum += p[wb * 4 + r];
            }
        sum += __shfl_xor(sum, 16);
        sum += __shfl_xor(sum, 32);
        float inv = __builtin_amdgcn_rcpf(sum);

        unsigned int pku[8];
        #pragma unroll
        for (int kk = 0; kk < 8; ++kk) pku[kk] = cvtpk_bf16(p[2 * kk], p[2 * kk + 1]);
        #pragma unroll
        for (int wb = 0; wb < 4; ++wb) {
            uint2 w2; w2.x = pku[2 * wb]; w2.y = pku[2 * wb + 1];
            *(uint2*)&ps_s[wid][c][wb * 16 + h * 4] = w2;
        }
        s16x8 pb0 = *(const s16x8*)&ps_s[wid][c][h * 8];
        s16x8 pb1 = *(const s16x8*)&ps_s[wid][c][32 + h * 8];

        float* zout = zrowp + (size_t)b * LWORD;
        #pragma unroll
        for (int mb = 0; mb < 2; ++mb) {
            f32x4 z = {0.f, 0.f, 0.f, 0.f};
            z = __builtin_amdgcn_mfma_f32_16x16x32_bf16(a2f[mb * 2 + 0], pb0, z, 0, 0, 0);
            z = __builtin_amdgcn_mfma_f32_16x16x32_bf16(a2f[mb * 2 + 1], pb1, z, 0, 0, 0);
            float4 v;
            v.x = z[0] * inv; v.y = z[1] * inv; v.z = z[2] * inv; v.w = z[3] * inv;
            *(float4*)(zout + mb * 16) = v;
        }

        if (h == 0) {
            idx_s[wid][k][c] = (float)wsel;
            if (cnt >= 2) {                   /* defer np-exact rescan */
                unsigned int pos = atomicAdd(ctr, 1u);
                unsigned int row = (unsigned int)(r0 + c);
                if (pos < LIST_CAP) list[pos] = (row << 7) | (unsigned int)b;
            }
        }
    }

    /* coalesced idx writeout: each lane emits one 32B chunk of a 128B row line */
    int rr = lane >> 2, j = lane & 3;
    float v0[4], v1[4];
    #pragma unroll
    for (int i = 0; i < 4; ++i) v0[i] = idx_s[wid][j * 8 + i][rr];
    #pragma unroll
    for (int i = 0; i < 4; ++i) v1[i] = idx_s[wid][j * 8 + 4 + i][rr];
    float* ibase = out + Z_ELEMS + (size_t)(r0 + rr) * NBOOKS + wid * 32 + j * 8;
    *(float4*)ibase       = *(float4*)v0;
    *(float4*)(ibase + 4) = *(float4*)v1;
}

/* ---------- kernel 3: np-exact rescan of flagged near-tie rows ---------- */
__global__ __launch_bounds__(256) void rescan_kernel(const float* __restrict__ x,
                                                     const float* __restrict__ cbT,
                                                     const float* __restrict__ c2T,
                                                     const unsigned int* __restrict__ ctr,
                                                     const unsigned int* __restrict__ list,
                                                     float* __restrict__ out) {
    unsigned int n = *ctr;
    if (n > LIST_CAP) n = LIST_CAP;
    for (unsigned int i = blockIdx.x * 256 + threadIdx.x; i < n; i += 64u * 256u) {
        unsigned int e = list[i];
        int row = (int)(e >> 7);
        int b   = (int)(e & 127u);
        const float* xrow = x + (size_t)row * DIMS + b * LWORD;
        float xr2[LWORD], sq[LWORD];
        #pragma unroll
        for (int q2 = 0; q2 < 8; ++q2)
            *(float4*)&xr2[q2 * 4] = *(const float4*)(xrow + q2 * 4);
        #pragma unroll
        for (int l = 0; l < LWORD; ++l) sq[l] = xr2[l] * xr2[l];
        float x2n = np_sum32(sq);
        float best = __builtin_inff();
        int wbest = 0;
        const float* Cb = cbT + (size_t)b * NWORDS * LWORD;
        for (int w2 = 0; w2 < NWORDS; ++w2) {
            const float* cw = Cb + (size_t)w2 * LWORD;
            double accd = 0.0;
            #pragma unroll
            for (int l = 0; l < LWORD; ++l)
                accd = fma((double)xr2[l], (double)cw[l], accd);
            float xcf = (float)accd;
            float dnp;
            {
#pragma clang fp contract(off)
                float s1 = x2n + c2T[b * NWORDS + w2];
                float s2 = 2.0f * xcf;
                dnp = s1 - s2;
            }
            if (dnp < best) { best = dnp; wbest = w2; }
        }
        out[Z_ELEMS + (size_t)row * NBOOKS + b] = (float)wbest;
    }
}

extern "C" void kernel_launch(void* const* d_in, const int* in_sizes, int n_in,
                              void* d_out, int out_size, void* d_ws, size_t ws_size,
                              hipStream_t stream) {
    const float* x = (const float*)d_in[0];
    const float* C = (const float*)d_in[1];
    float* out = (float*)d_out;
    char* ws = (char*)d_ws;
    float* cbT = (float*)(ws + CBT_OFF);
    float* c2T = (float*)(ws + C2T_OFF);
    s16x8* fr  = (s16x8*)(ws + FR_OFF);
    unsigned int* ctr  = (unsigned int*)(ws + CTR_OFF);
    unsigned int* list = (unsigned int*)(ws + LIST_OFF);

    prepC_kernel<<<128, 64, 0, stream>>>(C, cbT, c2T, fr, ctr);
    softpq_mfma<<<1024, 256, 0, stream>>>(x, fr, ctr, list, out);
    rescan_kernel<<<64, 256, 0, stream>>>(x, cbT, c2T, ctr, list, out);
}

// Round 11
// 160.668 us; speedup vs baseline: 2.4067x; 2.4067x over previous
//
#include <hip/hip_runtime.h>
#include <math.h>

#define NROWS   16384
#define NBOOKS  128
#define NWORDS  64
#define LWORD   32
#define DIMS    4096
#define T2K     28.8539008177792681472f   /* 20 * log2(e) */
#define Z_ELEMS 67108864ull               /* 16384*4096   */

typedef __attribute__((ext_vector_type(8))) short s16x8;
typedef __attribute__((ext_vector_type(4))) float f32x4;
typedef __attribute__((ext_vector_type(4))) unsigned int u32x4;

/* ws layout (bytes) */
#define CBT_OFF  0u           /* f32 [128][64][32] np-normalized codewords      */
#define C2T_OFF  1048576u     /* f32 [128][64]                                  */
#define FR_OFF   1114112u     /* merged frags: [(b*4+wb)*64+lane][4 x 16B]      */
#define CTR_OFF  3211264u     /* u32 rescan counter                             */
#define LIST_OFF 3211392u     /* u32[131072] packed (row<<7)|b                  */
#define LIST_CAP 131072u

__device__ __forceinline__ unsigned short f2bf(float f) {
    unsigned int u = __float_as_uint(f);
    unsigned int r = (u + 0x7FFFu + ((u >> 16) & 1u)) >> 16;   /* RNE */
    return (unsigned short)r;
}
__device__ __forceinline__ float bf2f(unsigned short s) {
    return __uint_as_float(((unsigned int)s) << 16);
}
__device__ __forceinline__ unsigned int cvtpk_bf16(float lo, float hi) {
    unsigned int r;
    asm("v_cvt_pk_bf16_f32 %0, %1, %2" : "=v"(r) : "v"(lo), "v"(hi));  /* RNE */
    return r;
}

/* numpy pairwise-sum replica for n=32 f32 (exact order, no contraction) */
__device__ __forceinline__ float np_sum32(const float* a) {
#pragma clang fp contract(off)
    float r0 = a[0], r1 = a[1], r2 = a[2], r3 = a[3];
    float r4 = a[4], r5 = a[5], r6 = a[6], r7 = a[7];
    r0 += a[8];  r1 += a[9];  r2 += a[10]; r3 += a[11];
    r4 += a[12]; r5 += a[13]; r6 += a[14]; r7 += a[15];
    r0 += a[16]; r1 += a[17]; r2 += a[18]; r3 += a[19];
    r4 += a[20]; r5 += a[21]; r6 += a[22]; r7 += a[23];
    r0 += a[24]; r1 += a[25]; r2 += a[26]; r3 += a[27];
    r4 += a[28]; r5 += a[29]; r6 += a[30]; r7 += a[31];
    return ((r0 + r1) + (r2 + r3)) + ((r4 + r5) + (r6 + r7));
}

/* ---------- kernel 1: fused np-exact normalize + merged frag build (verified r7) ---------- */
__global__ __launch_bounds__(64) void prepC_kernel(const float* __restrict__ C,
                                                   float* __restrict__ cbT,
                                                   float* __restrict__ c2T,
                                                   s16x8* __restrict__ fr,
                                                   unsigned int* __restrict__ ctr) {
    __shared__ float cb_s[NWORDS][33];
    __shared__ float c2_s[NWORDS];
    int b = blockIdx.x;
    int w = threadIdx.x;
    if (b == 0 && w == 0) ctr[0] = 0u;

    float cb[LWORD];
    float c2;
    {
#pragma clang fp contract(off)
        const float* src = C + (size_t)w * DIMS + b * LWORD;
        float v[LWORD];
        #pragma unroll
        for (int q = 0; q < 8; ++q)
            *(float4*)&v[4 * q] = *(const float4*)&src[4 * q];
        float sq[LWORD];
        #pragma unroll
        for (int l = 0; l < LWORD; ++l) sq[l] = v[l] * v[l];
        float nrm = fmaxf(sqrtf(np_sum32(sq)), 1e-12f);
        #pragma unroll
        for (int l = 0; l < LWORD; ++l) cb[l] = v[l] / nrm;
        float sq2[LWORD];
        #pragma unroll
        for (int l = 0; l < LWORD; ++l) sq2[l] = cb[l] * cb[l];
        c2 = np_sum32(sq2);
    }
    float* dst = cbT + ((size_t)b * NWORDS + w) * LWORD;
    #pragma unroll
    for (int q = 0; q < 8; ++q)
        *(float4*)&dst[4 * q] = *(const float4*)&cb[4 * q];
    c2T[b * NWORDS + w] = c2;
    #pragma unroll
    for (int l = 0; l < LWORD; ++l) cb_s[w][l] = cb[l];
    c2_s[w] = c2;
    __syncthreads();

    int lr = w & 15, lh = w >> 4;
    #pragma unroll
    for (int wb = 0; wb < 4; ++wb) {
        s16x8 ch8, cl8, a28;
        #pragma unroll
        for (int i = 0; i < 8; ++i) {
            float f = cb_s[wb * 16 + lr][lh * 8 + i];
            unsigned short hh = f2bf(f);
            ch8[i] = (short)hh;
            cl8[i] = (short)f2bf(f - bf2f(hh));
            a28[i] = (short)f2bf(cb_s[(wb & 1) * 32 + lh * 8 + i][(wb >> 1) * 16 + lr]);
        }
        f32x4 civ = {-0.5f * c2_s[wb * 16 + lh * 4 + 0],
                     -0.5f * c2_s[wb * 16 + lh * 4 + 1],
                     -0.5f * c2_s[wb * 16 + lh * 4 + 2],
                     -0.5f * c2_s[wb * 16 + lh * 4 + 3]};
        s16x8* d = fr + ((size_t)(b * 4 + wb) * 64 + w) * 4;
        d[0] = ch8;
        d[1] = cl8;
        d[2] = a28;
        d[3] = __builtin_bit_cast(s16x8, civ);
    }
}

/* ---------- per-group tail (verbatim r6 numerics; direct idx write) ---------- */
#define GROUP_TAIL(ACC, G)                                                             \
  {                                                                                    \
    float q0 = fmaxf(fmaxf(ACC[0][0], ACC[0][1]), ACC[0][2]);                          \
    float q1 = fmaxf(fmaxf(ACC[0][3], ACC[1][0]), ACC[1][1]);                          \
    float q2 = fmaxf(fmaxf(ACC[1][2], ACC[1][3]), ACC[2][0]);                          \
    float q3 = fmaxf(fmaxf(ACC[2][1], ACC[2][2]), ACC[2][3]);                          \
    float q4 = fmaxf(fmaxf(ACC[3][0], ACC[3][1]), ACC[3][2]);                          \
    float m1 = fmaxf(fmaxf(fmaxf(q0, q1), q2), fmaxf(fmaxf(q3, q4), ACC[3][3]));       \
    m1 = fmaxf(m1, __shfl_xor(m1, 16));                                                \
    m1 = fmaxf(m1, __shfl_xor(m1, 32));                                                \
    float thr = m1 - 2e-4f;                                                            \
    int cnt = 0;                                                                       \
    _Pragma("unroll")                                                                  \
    for (int wb = 0; wb < 4; ++wb)                                                     \
      _Pragma("unroll")                                                                \
      for (int r = 0; r < 4; ++r) cnt += (ACC[wb][r] > thr) ? 1 : 0;                   \
    cnt += __shfl_xor(cnt, 16);                                                        \
    cnt += __shfl_xor(cnt, 32);                                                        \
    int wsel = 9999;                                                                   \
    _Pragma("unroll")                                                                  \
    for (int wb = 0; wb < 4; ++wb)                                                     \
      _Pragma("unroll")                                                                \
      for (int r = 0; r < 4; ++r)                                                      \
        if (ACC[wb][r] == m1) wsel = min(wsel, wb * 16 + h * 4 + r);                   \
    wsel = min(wsel, __shfl_xor(wsel, 16));                                            \
    wsel = min(wsel, __shfl_xor(wsel, 32));                                            \
    float mqt = m1 * (-T2K);                                                           \
    float p[16];                                                                       \
    float sum = 0.f;                                                                   \
    _Pragma("unroll")                                                                  \
    for (int wb = 0; wb < 4; ++wb)                                                     \
      _Pragma("unroll")                                                                \
      for (int r = 0; r < 4; ++r) {                                                    \
        p[wb * 4 + r] = __builtin_amdgcn_exp2f(fmaf(T2K, ACC[wb][r], mqt));            \
        sum += p[wb * 4 + r];                                                          \
      }                                                                                \
    sum += __shfl_xor(sum, 16);                                                        \
    sum += __shfl_xor(sum, 32);                                                        \
    float inv = __builtin_amdgcn_rcpf(sum);                                            \
    unsigned int pku[8];                                                               \
    _Pragma("unroll")                                                                  \
    for (int k = 0; k < 8; ++k) pku[k] = cvtpk_bf16(p[2 * k], p[2 * k + 1]);           \
    _Pragma("unroll")                                                                  \
    for (int wb = 0; wb < 4; ++wb) {                                                   \
      uint2 w2; w2.x = pku[2 * wb]; w2.y = pku[2 * wb + 1];                            \
      *(uint2*)&ps_s[wid][(G) & 1][c][wb * 16 + h * 4] = w2;                           \
    }                                                                                  \
    s16x8 pb0 = *(const s16x8*)&ps_s[wid][(G) & 1][c][h * 8];                          \
    s16x8 pb1 = *(const s16x8*)&ps_s[wid][(G) & 1][c][32 + h * 8];                     \
    float* zout = zbase + (size_t)(G) * 16 * DIMS;                                     \
    _Pragma("unroll")                                                                  \
    for (int mb = 0; mb < 2; ++mb) {                                                   \
      f32x4 z = {0.f, 0.f, 0.f, 0.f};                                                  \
      z = __builtin_amdgcn_mfma_f32_16x16x32_bf16(a2f[mb * 2 + 0], pb0, z, 0, 0, 0);   \
      z = __builtin_amdgcn_mfma_f32_16x16x32_bf16(a2f[mb * 2 + 1], pb1, z, 0, 0, 0);   \
      float4 v;                                                                        \
      v.x = z[0] * inv; v.y = z[1] * inv; v.z = z[2] * inv; v.w = z[3] * inv;          \
      *(float4*)(zout + mb * 16) = v;                                                  \
    }                                                                                  \
    if (h == 0) {                                                                      \
      int row = n0 + wid * 64 + (G) * 16 + c;                                          \
      out[Z_ELEMS + (size_t)row * NBOOKS + b] = (float)wsel;                           \
      if (cnt >= 2) {                                                                  \
        unsigned int pos = atomicAdd(ctr, 1u);                                         \
        if (pos < LIST_CAP) list[pos] = ((unsigned int)row << 7) | (unsigned int)b;    \
      }                                                                                \
    }                                                                                  \
  }

/* ---------- kernel 2: hot path — prefetch-4, paired-group pipeline (r6 structure) ---------- */
__global__ __launch_bounds__(256, 3) void softpq_mfma(const float* __restrict__ x,
                                                      const s16x8* __restrict__ fr,
                                                      unsigned int* __restrict__ ctr,
                                                      unsigned int* __restrict__ list,
                                                      float* __restrict__ out) {
    __shared__ __align__(16) unsigned short ps_s[4][2][16][72];   /* 18432 B */

    int u = blockIdx.x;                      /* XCD-chunked */
    int L = (u & 7) * 1024 + (u >> 3);
    int b  = L >> 6;
    int n0 = (L & 63) * 256;
    int t  = threadIdx.x;
    int lane = t & 63, wid = t >> 6;
    int h = lane >> 4, c = lane & 15;

    /* 1) issue ALL x loads (8 in flight) */
    const float* xbase = x + (size_t)(n0 + wid * 64 + c) * DIMS + b * LWORD + h * 8;
    float4 xa[4], xb[4];
    #pragma unroll
    for (int g = 0; g < 4; ++g) {
        xa[g] = *(const float4*)(xbase + (size_t)g * 16 * DIMS);
        xb[g] = *(const float4*)(xbase + (size_t)g * 16 * DIMS + 4);
    }

    /* 2) merged frag loads (L2-hot, 4 x 16B contiguous per lane per wb) */
    const s16x8* fp = fr + ((size_t)b * 4 * 64 + lane) * 4;
    s16x8 chf[4], clf[4], a2f[4];
    f32x4 ci[4];
    #pragma unroll
    for (int wb = 0; wb < 4; ++wb) {
        const s16x8* q = fp + (size_t)wb * 256;
        chf[wb] = q[0];
        clf[wb] = q[1];
        a2f[wb] = q[2];
        ci[wb]  = __builtin_bit_cast(f32x4, q[3]);
    }

    /* 3) eager split into bf16 hi + residual */
    unsigned int xh[4][4], xl[4][4];
    #pragma unroll
    for (int g = 0; g < 4; ++g) {
        float xf[8] = {xa[g].x, xa[g].y, xa[g].z, xa[g].w,
                       xb[g].x, xb[g].y, xb[g].z, xb[g].w};
        #pragma unroll
        for (int j = 0; j < 4; ++j) {
            float f0 = xf[2 * j], f1 = xf[2 * j + 1];
            unsigned int ph = cvtpk_bf16(f0, f1);
            float h0 = __uint_as_float(ph << 16);
            float h1 = __uint_as_float(ph & 0xffff0000u);
            xh[g][j] = ph;
            xl[g][j] = cvtpk_bf16(f0 - h0, f1 - h1);
        }
    }

    float* zbase = out + (size_t)(n0 + wid * 64 + c) * DIMS + b * LWORD + h * 4;

    /* paired-group pipeline */
    #pragma unroll
    for (int gp = 0; gp < 2; ++gp) {
        int g0 = gp * 2, g1 = gp * 2 + 1;
        u32x4 th0 = {xh[g0][0], xh[g0][1], xh[g0][2], xh[g0][3]};
        u32x4 tl0 = {xl[g0][0], xl[g0][1], xl[g0][2], xl[g0][3]};
        u32x4 th1 = {xh[g1][0], xh[g1][1], xh[g1][2], xh[g1][3]};
        u32x4 tl1 = {xl[g1][0], xl[g1][1], xl[g1][2], xl[g1][3]};
        s16x8 xh0 = __builtin_bit_cast(s16x8, th0);
        s16x8 xl0 = __builtin_bit_cast(s16x8, tl0);
        s16x8 xh1 = __builtin_bit_cast(s16x8, th1);
        s16x8 xl1 = __builtin_bit_cast(s16x8, tl1);

        __builtin_amdgcn_s_setprio(1);
        f32x4 acc0[4], acc1[4];
        #pragma unroll
        for (int wb = 0; wb < 4; ++wb) {
            f32x4 a = ci[wb];
            a = __builtin_amdgcn_mfma_f32_16x16x32_bf16(chf[wb], xh0, a, 0, 0, 0);
            a = __builtin_amdgcn_mfma_f32_16x16x32_bf16(chf[wb], xl0, a, 0, 0, 0);
            a = __builtin_amdgcn_mfma_f32_16x16x32_bf16(clf[wb], xh0, a, 0, 0, 0);
            acc0[wb] = a;
        }
        #pragma unroll
        for (int wb = 0; wb < 4; ++wb) {
            f32x4 a = ci[wb];
            a = __builtin_amdgcn_mfma_f32_16x16x32_bf16(chf[wb], xh1, a, 0, 0, 0);
            a = __builtin_amdgcn_mfma_f32_16x16x32_bf16(chf[wb], xl1, a, 0, 0, 0);
            a = __builtin_amdgcn_mfma_f32_16x16x32_bf16(clf[wb], xh1, a, 0, 0, 0);
            acc1[wb] = a;
        }
        __builtin_amdgcn_s_setprio(0);

        GROUP_TAIL(acc0, g0)
        GROUP_TAIL(acc1, g1)
    }
}

/* ---------- kernel 3: wave-cooperative np-exact rescan (lane = word) ---------- */
__global__ __launch_bounds__(256) void rescan_wave(const float* __restrict__ x,
                                                   const float* __restrict__ cbT,
                                                   const float* __restrict__ c2T,
                                                   const unsigned int* __restrict__ ctr,
                                                   const unsigned int* __restrict__ list,
                                                   float* __restrict__ out) {
    unsigned int n = *ctr;
    if (n > LIST_CAP) n = LIST_CAP;
    unsigned int wgl = blockIdx.x * 4u + (threadIdx.x >> 6);
    unsigned int nw  = gridDim.x * 4u;
    int lane = threadIdx.x & 63;

    for (unsigned int i = wgl; i < n; i += nw) {
        unsigned int e = list[i];
        int row = (int)(e >> 7);
        int b   = (int)(e & 127u);

        const float* xrow = x + (size_t)row * DIMS + b * LWORD;
        float xr2[LWORD];
        #pragma unroll
        for (int q = 0; q < 8; ++q)
            *(float4*)&xr2[q * 4] = *(const float4*)(xrow + q * 4);
        float sq[LWORD];
        #pragma unroll
        for (int l = 0; l < LWORD; ++l) sq[l] = xr2[l] * xr2[l];
        float x2n = np_sum32(sq);

        /* lane = word: f64 correctly-rounded dot with this word's codeword */
        const float* cw = cbT + ((size_t)b * NWORDS + lane) * LWORD;
        float cwv[LWORD];
        #pragma unroll
        for (int q = 0; q < 8; ++q)
            *(float4*)&cwv[q * 4] = *(const float4*)(cw + q * 4);
        double a0 = 0.0, a1 = 0.0, a2 = 0.0, a3 = 0.0;
        #pragma unroll
        for (int l = 0; l < 8; ++l) {
            a0 = fma((double)xr2[l],      (double)cwv[l],      a0);
            a1 = fma((double)xr2[l + 8],  (double)cwv[l + 8],  a1);
            a2 = fma((double)xr2[l + 16], (double)cwv[l + 16], a2);
            a3 = fma((double)xr2[l + 24], (double)cwv[l + 24], a3);
        }
        float xcf = (float)((a0 + a1) + (a2 + a3));
        float dnp;
        {
#pragma clang fp contract(off)
            float s1 = x2n + c2T[b * NWORDS + lane];
            float s2 = 2.0f * xcf;
            dnp = s1 - s2;
        }
        /* min across 64 lanes + np first-min tie rule */
        float dmin = dnp;
        dmin = fminf(dmin, __shfl_xor(dmin, 1));
        dmin = fminf(dmin, __shfl_xor(dmin, 2));
        dmin = fminf(dmin, __shfl_xor(dmin, 4));
        dmin = fminf(dmin, __shfl_xor(dmin, 8));
        dmin = fminf(dmin, __shfl_xor(dmin, 16));
        dmin = fminf(dmin, __shfl_xor(dmin, 32));
        unsigned long long ball = __ballot(dnp == dmin);
        int wbest = __ffsll((long long)ball) - 1;
        if (lane == 0)
            out[Z_ELEMS + (size_t)row * NBOOKS + b] = (float)wbest;
    }
}

extern "C" void kernel_launch(void* const* d_in, const int* in_sizes, int n_in,
                              void* d_out, int out_size, void* d_ws, size_t ws_size,
                              hipStream_t stream) {
    const float* x = (const float*)d_in[0];
    const float* C = (const float*)d_in[1];
    float* out = (float*)d_out;
    char* ws = (char*)d_ws;
    float* cbT = (float*)(ws + CBT_OFF);
    float* c2T = (float*)(ws + C2T_OFF);
    s16x8* fr  = (s16x8*)(ws + FR_OFF);
    unsigned int* ctr  = (unsigned int*)(ws + CTR_OFF);
    unsigned int* list = (unsigned int*)(ws + LIST_OFF);

    prepC_kernel<<<128, 64, 0, stream>>>(C, cbT, c2T, fr, ctr);
    softpq_mfma<<<8192, 256, 0, stream>>>(x, fr, ctr, list, out);
    rescan_wave<<<512, 256, 0, stream>>>(x, cbT, c2T, ctr, list, out);
}

// Round 12
// 156.574 us; speedup vs baseline: 2.4697x; 1.0261x over previous
//
#include <hip/hip_runtime.h>
#include <math.h>

#define NROWS   16384
#define NBOOKS  128
#define NWORDS  64
#define LWORD   32
#define DIMS    4096
#define T2K     28.8539008177792681472f   /* 20 * log2(e) */
#define Z_ELEMS 67108864ull               /* 16384*4096   */

typedef __attribute__((ext_vector_type(8))) short s16x8;
typedef __attribute__((ext_vector_type(4))) float f32x4;
typedef __attribute__((ext_vector_type(4))) unsigned int u32x4;

/* ws layout (bytes) */
#define CBT_OFF  0u           /* f32 [128][64][32] np-normalized codewords       */
#define C2T_OFF  1048576u     /* f32 [128][64]                                   */
#define FR_OFF   1114112u     /* frags: [book][wb*4+slot][lane] s16x8, 16KB/book */
#define CTR_OFF  3211264u     /* u32 rescan counter                              */
#define LIST_OFF 3211392u     /* u32[131072] packed (row<<7)|b                   */
#define LIST_CAP 131072u

__device__ __forceinline__ unsigned short f2bf(float f) {
    unsigned int u = __float_as_uint(f);
    unsigned int r = (u + 0x7FFFu + ((u >> 16) & 1u)) >> 16;   /* RNE */
    return (unsigned short)r;
}
__device__ __forceinline__ float bf2f(unsigned short s) {
    return __uint_as_float(((unsigned int)s) << 16);
}
__device__ __forceinline__ unsigned int cvtpk_bf16(float lo, float hi) {
    unsigned int r;
    asm("v_cvt_pk_bf16_f32 %0, %1, %2" : "=v"(r) : "v"(lo), "v"(hi));  /* RNE */
    return r;
}

/* numpy pairwise-sum replica for n=32 f32 (exact order, no contraction) */
__device__ __forceinline__ float np_sum32(const float* a) {
#pragma clang fp contract(off)
    float r0 = a[0], r1 = a[1], r2 = a[2], r3 = a[3];
    float r4 = a[4], r5 = a[5], r6 = a[6], r7 = a[7];
    r0 += a[8];  r1 += a[9];  r2 += a[10]; r3 += a[11];
    r4 += a[12]; r5 += a[13]; r6 += a[14]; r7 += a[15];
    r0 += a[16]; r1 += a[17]; r2 += a[18]; r3 += a[19];
    r4 += a[20]; r5 += a[21]; r6 += a[22]; r7 += a[23];
    r0 += a[24]; r1 += a[25]; r2 += a[26]; r3 += a[27];
    r4 += a[28]; r5 += a[29]; r6 += a[30]; r7 += a[31];
    return ((r0 + r1) + (r2 + r3)) + ((r4 + r5) + (r6 + r7));
}

/* ---------- kernel 1: fused np-exact normalize + frag build (new layout) ---------- */
__global__ __launch_bounds__(64) void prepC_kernel(const float* __restrict__ C,
                                                   float* __restrict__ cbT,
                                                   float* __restrict__ c2T,
                                                   s16x8* __restrict__ fr,
                                                   unsigned int* __restrict__ ctr) {
    __shared__ float cb_s[NWORDS][33];
    __shared__ float c2_s[NWORDS];
    int b = blockIdx.x;
    int w = threadIdx.x;
    if (b == 0 && w == 0) ctr[0] = 0u;

    float cb[LWORD];
    float c2;
    {   /* np-exact normalize — verbatim verified math */
#pragma clang fp contract(off)
        const float* src = C + (size_t)w * DIMS + b * LWORD;
        float v[LWORD];
        #pragma unroll
        for (int q = 0; q < 8; ++q)
            *(float4*)&v[4 * q] = *(const float4*)&src[4 * q];
        float sq[LWORD];
        #pragma unroll
        for (int l = 0; l < LWORD; ++l) sq[l] = v[l] * v[l];
        float nrm = fmaxf(sqrtf(np_sum32(sq)), 1e-12f);
        #pragma unroll
        for (int l = 0; l < LWORD; ++l) cb[l] = v[l] / nrm;
        float sq2[LWORD];
        #pragma unroll
        for (int l = 0; l < LWORD; ++l) sq2[l] = cb[l] * cb[l];
        c2 = np_sum32(sq2);
    }
    float* dst = cbT + ((size_t)b * NWORDS + w) * LWORD;
    #pragma unroll
    for (int q = 0; q < 8; ++q)
        *(float4*)&dst[4 * q] = *(const float4*)&cb[4 * q];
    c2T[b * NWORDS + w] = c2;
    #pragma unroll
    for (int l = 0; l < LWORD; ++l) cb_s[w][l] = cb[l];
    c2_s[w] = c2;
    __syncthreads();

    int lr = w & 15, lh = w >> 4;
    s16x8* frb = fr + (size_t)b * 1024;       /* 16KB per book */
    #pragma unroll
    for (int wb = 0; wb < 4; ++wb) {
        s16x8 ch8, cl8, a28;
        #pragma unroll
        for (int i = 0; i < 8; ++i) {
            float f = cb_s[wb * 16 + lr][lh * 8 + i];
            unsigned short hh = f2bf(f);
            ch8[i] = (short)hh;
            cl8[i] = (short)f2bf(f - bf2f(hh));
            a28[i] = (short)f2bf(cb_s[(wb & 1) * 32 + lh * 8 + i][(wb >> 1) * 16 + lr]);
        }
        f32x4 civ = {-0.5f * c2_s[wb * 16 + lh * 4 + 0],
                     -0.5f * c2_s[wb * 16 + lh * 4 + 1],
                     -0.5f * c2_s[wb * 16 + lh * 4 + 2],
                     -0.5f * c2_s[wb * 16 + lh * 4 + 3]};
        frb[(wb * 4 + 0) * 64 + w] = ch8;
        frb[(wb * 4 + 1) * 64 + w] = cl8;
        frb[(wb * 4 + 2) * 64 + w] = a28;
        frb[(wb * 4 + 3) * 64 + w] = __builtin_bit_cast(s16x8, civ);
    }
}

/* ---------- kernel 2: hot path — 8 waves x 16 rows, frags in LDS, <=64 VGPR ---------- */
__global__ __launch_bounds__(512, 8) void softpq_mfma(const float* __restrict__ x,
                                                      const s16x8* __restrict__ fr,
                                                      unsigned int* __restrict__ ctr,
                                                      unsigned int* __restrict__ list,
                                                      float* __restrict__ out) {
    __shared__ __align__(16) s16x8 frag_s[1024];                 /* 16384 B */
    __shared__ __align__(16) unsigned short ps_s[8][16][72];     /* 18432 B */

    int u = blockIdx.x;                      /* XCD-chunked: 16384 blocks, %8==0 */
    int L = (u & 7) * 2048 + (u >> 3);
    int b    = L >> 7;
    int tile = L & 127;
    int n0   = tile * 128;
    int t    = threadIdx.x;
    int lane = t & 63, wid = t >> 6;
    int h = lane >> 4, c = lane & 15;
    int row = n0 + wid * 16 + c;

    /* 1) x loads first (HBM latency overlaps frag staging) */
    const float* xp = x + (size_t)row * DIMS + b * LWORD + h * 8;
    float4 xa = *(const float4*)xp;
    float4 xb = *(const float4*)(xp + 4);

    /* 2) stage book's 16KB frag record: 512 thr x 32B, conflict-free */
    {
        const s16x8* g = fr + (size_t)b * 1024 + t * 2;
        s16x8 g0 = g[0];
        s16x8 g1 = g[1];
        frag_s[t * 2]     = g0;
        frag_s[t * 2 + 1] = g1;
    }
    __syncthreads();

    /* 3) split x into bf16 hi + residual (verbatim) */
    float xf[8] = {xa.x, xa.y, xa.z, xa.w, xb.x, xb.y, xb.z, xb.w};
    unsigned int xhu[4], xlu[4];
    #pragma unroll
    for (int j = 0; j < 4; ++j) {
        float f0 = xf[2 * j], f1 = xf[2 * j + 1];
        unsigned int ph = cvtpk_bf16(f0, f1);
        float h0 = __uint_as_float(ph << 16);
        float h1 = __uint_as_float(ph & 0xffff0000u);
        xhu[j] = ph;
        xlu[j] = cvtpk_bf16(f0 - h0, f1 - h1);
    }
    u32x4 thv = {xhu[0], xhu[1], xhu[2], xhu[3]};
    u32x4 tlv = {xlu[0], xlu[1], xlu[2], xlu[3]};
    s16x8 xhv = __builtin_bit_cast(s16x8, thv);
    s16x8 xlv = __builtin_bit_cast(s16x8, tlv);

    /* 4) 12 S-MFMAs, frags streamed from LDS; acc = dot - c2/2 */
    f32x4 acc[4];
    __builtin_amdgcn_s_setprio(1);
    #pragma unroll
    for (int wb = 0; wb < 4; ++wb) {
        s16x8 chf = frag_s[(wb * 4 + 0) * 64 + lane];
        s16x8 clf = frag_s[(wb * 4 + 1) * 64 + lane];
        f32x4 a   = __builtin_bit_cast(f32x4, frag_s[(wb * 4 + 3) * 64 + lane]);
        a = __builtin_amdgcn_mfma_f32_16x16x32_bf16(chf, xhv, a, 0, 0, 0);
        a = __builtin_amdgcn_mfma_f32_16x16x32_bf16(chf, xlv, a, 0, 0, 0);
        a = __builtin_amdgcn_mfma_f32_16x16x32_bf16(clf, xhv, a, 0, 0, 0);
        acc[wb] = a;
    }
    __builtin_amdgcn_s_setprio(0);

    /* ---- tail: verbatim verified numerics ---- */
    float q0 = fmaxf(fmaxf(acc[0][0], acc[0][1]), acc[0][2]);
    float q1 = fmaxf(fmaxf(acc[0][3], acc[1][0]), acc[1][1]);
    float q2 = fmaxf(fmaxf(acc[1][2], acc[1][3]), acc[2][0]);
    float q3 = fmaxf(fmaxf(acc[2][1], acc[2][2]), acc[2][3]);
    float q4 = fmaxf(fmaxf(acc[3][0], acc[3][1]), acc[3][2]);
    float m1 = fmaxf(fmaxf(fmaxf(q0, q1), q2), fmaxf(fmaxf(q3, q4), acc[3][3]));
    m1 = fmaxf(m1, __shfl_xor(m1, 16));
    m1 = fmaxf(m1, __shfl_xor(m1, 32));

    float thr = m1 - 2e-4f;
    int cnt = 0;
    #pragma unroll
    for (int wb = 0; wb < 4; ++wb)
        #pragma unroll
        for (int r = 0; r < 4; ++r) cnt += (acc[wb][r] > thr) ? 1 : 0;
    cnt += __shfl_xor(cnt, 16);
    cnt += __shfl_xor(cnt, 32);

    int wsel = 9999;
    #pragma unroll
    for (int wb = 0; wb < 4; ++wb)
        #pragma unroll
        for (int r = 0; r < 4; ++r)
            if (acc[wb][r] == m1) wsel = min(wsel, wb * 16 + h * 4 + r);
    wsel = min(wsel, __shfl_xor(wsel, 16));
    wsel = min(wsel, __shfl_xor(wsel, 32));

    float mqt = m1 * (-T2K);
    float p[16];
    float sum = 0.f;
    #pragma unroll
    for (int wb = 0; wb < 4; ++wb)
        #pragma unroll
        for (int r = 0; r < 4; ++r) {
            p[wb * 4 + r] = __builtin_amdgcn_exp2f(fmaf(T2K, acc[wb][r], mqt));
            sum += p[wb * 4 + r];
        }
    sum += __shfl_xor(sum, 16);
    sum += __shfl_xor(sum, 32);
    float inv = __builtin_amdgcn_rcpf(sum);

    unsigned int pku[8];
    #pragma unroll
    for (int k = 0; k < 8; ++k) pku[k] = cvtpk_bf16(p[2 * k], p[2 * k + 1]);
    #pragma unroll
    for (int wb = 0; wb < 4; ++wb) {
        uint2 w2; w2.x = pku[2 * wb]; w2.y = pku[2 * wb + 1];
        *(uint2*)&ps_s[wid][c][wb * 16 + h * 4] = w2;
    }
    s16x8 pb0 = *(const s16x8*)&ps_s[wid][c][h * 8];
    s16x8 pb1 = *(const s16x8*)&ps_s[wid][c][32 + h * 8];

    /* 4 Z-MFMAs, A-frags from LDS */
    float* zout = out + (size_t)row * DIMS + b * LWORD + h * 4;
    #pragma unroll
    for (int mb = 0; mb < 2; ++mb) {
        s16x8 a20 = frag_s[((mb * 2 + 0) * 4 + 2) * 64 + lane];
        s16x8 a21 = frag_s[((mb * 2 + 1) * 4 + 2) * 64 + lane];
        f32x4 z = {0.f, 0.f, 0.f, 0.f};
        z = __builtin_amdgcn_mfma_f32_16x16x32_bf16(a20, pb0, z, 0, 0, 0);
        z = __builtin_amdgcn_mfma_f32_16x16x32_bf16(a21, pb1, z, 0, 0, 0);
        float4 v;
        v.x = z[0] * inv; v.y = z[1] * inv; v.z = z[2] * inv; v.w = z[3] * inv;
        *(float4*)(zout + mb * 16) = v;
    }

    if (h == 0) {
        out[Z_ELEMS + (size_t)row * NBOOKS + b] = (float)wsel;
        if (cnt >= 2) {                       /* defer np-exact rescan */
            unsigned int pos = atomicAdd(ctr, 1u);
            if (pos < LIST_CAP) list[pos] = ((unsigned int)row << 7) | (unsigned int)b;
        }
    }
}

/* ---------- kernel 3: wave-cooperative np-exact rescan (lane = word) ---------- */
__global__ __launch_bounds__(256) void rescan_wave(const float* __restrict__ x,
                                                   const float* __restrict__ cbT,
                                                   const float* __restrict__ c2T,
                                                   const unsigned int* __restrict__ ctr,
                                                   const unsigned int* __restrict__ list,
                                                   float* __restrict__ out) {
    unsigned int n = *ctr;
    if (n > LIST_CAP) n = LIST_CAP;
    unsigned int wgl = blockIdx.x * 4u + (threadIdx.x >> 6);
    unsigned int nw  = gridDim.x * 4u;
    int lane = threadIdx.x & 63;

    for (unsigned int i = wgl; i < n; i += nw) {
        unsigned int e = list[i];
        int row = (int)(e >> 7);
        int b   = (int)(e & 127u);

        const float* xrow = x + (size_t)row * DIMS + b * LWORD;
        float xr2[LWORD];
        #pragma unroll
        for (int q = 0; q < 8; ++q)
            *(float4*)&xr2[q * 4] = *(const float4*)(xrow + q * 4);
        float sq[LWORD];
        #pragma unroll
        for (int l = 0; l < LWORD; ++l) sq[l] = xr2[l] * xr2[l];
        float x2n = np_sum32(sq);

        const float* cw = cbT + ((size_t)b * NWORDS + lane) * LWORD;
        float cwv[LWORD];
        #pragma unroll
        for (int q = 0; q < 8; ++q)
            *(float4*)&cwv[q * 4] = *(const float4*)(cw + q * 4);
        double a0 = 0.0, a1 = 0.0, a2 = 0.0, a3 = 0.0;
        #pragma unroll
        for (int l = 0; l < 8; ++l) {
            a0 = fma((double)xr2[l],      (double)cwv[l],      a0);
            a1 = fma((double)xr2[l + 8],  (double)cwv[l + 8],  a1);
            a2 = fma((double)xr2[l + 16], (double)cwv[l + 16], a2);
            a3 = fma((double)xr2[l + 24], (double)cwv[l + 24], a3);
        }
        float xcf = (float)((a0 + a1) + (a2 + a3));
        float dnp;
        {
#pragma clang fp contract(off)
            float s1 = x2n + c2T[b * NWORDS + lane];
            float s2 = 2.0f * xcf;
            dnp = s1 - s2;
        }
        float dmin = dnp;
        dmin = fminf(dmin, __shfl_xor(dmin, 1));
        dmin = fminf(dmin, __shfl_xor(dmin, 2));
        dmin = fminf(dmin, __shfl_xor(dmin, 4));
        dmin = fminf(dmin, __shfl_xor(dmin, 8));
        dmin = fminf(dmin, __shfl_xor(dmin, 16));
        dmin = fminf(dmin, __shfl_xor(dmin, 32));
        unsigned long long ball = __ballot(dnp == dmin);
        int wbest = __ffsll((long long)ball) - 1;
        if (lane == 0)
            out[Z_ELEMS + (size_t)row * NBOOKS + b] = (float)wbest;
    }
}

extern "C" void kernel_launch(void* const* d_in, const int* in_sizes, int n_in,
                              void* d_out, int out_size, void* d_ws, size_t ws_size,
                              hipStream_t stream) {
    const float* x = (const float*)d_in[0];
    const float* C = (const float*)d_in[1];
    float* out = (float*)d_out;
    char* ws = (char*)d_ws;
    float* cbT = (float*)(ws + CBT_OFF);
    float* c2T = (float*)(ws + C2T_OFF);
    s16x8* fr  = (s16x8*)(ws + FR_OFF);
    unsigned int* ctr  = (unsigned int*)(ws + CTR_OFF);
    unsigned int* list = (unsigned int*)(ws + LIST_OFF);

    prepC_kernel<<<128, 64, 0, stream>>>(C, cbT, c2T, fr, ctr);
    softpq_mfma<<<16384, 512, 0, stream>>>(x, fr, ctr, list, out);
    rescan_wave<<<512, 256, 0, stream>>>(x, cbT, c2T, ctr, list, out);
}